// Round 11
// baseline (207.720 us; speedup 1.0000x reference)
//
#include <hip/hip_runtime.h>
#include <hip/hip_bf16.h>

typedef __bf16 bf16;
typedef __bf16 bf16x4 __attribute__((ext_vector_type(4)));
typedef __bf16 bf16x8 __attribute__((ext_vector_type(8)));
typedef float  f32x4  __attribute__((ext_vector_type(4)));

#define BSZ   256
#define SEQ   256
#define DIN   512
#define DEMB  1024
#define KSEL  76
#define MROWS (BSZ * KSEL)   // 19456
#define MT128 (MROWS / 128)  // 152
#define PARTQ (MT128 * 512)
#define NRED  38             // stage-A reduce blocks (152/4)

__device__ __forceinline__ void gload16(const void* g, void* l) {
  __builtin_amdgcn_global_load_lds((const __attribute__((address_space(1))) void*)g,
                                   (__attribute__((address_space(3))) void*)l, 16, 0, 0);
}

// monotone float<->uint order-preserving encode for atomicMax.
// All enc() values are > 0, so zero-init acts as the -inf sentinel
// (every key provably receives >=1 update since plen[b] >= 1).
__device__ __forceinline__ unsigned enc(float v) {
  unsigned u = __float_as_uint(v);
  return (u & 0x80000000u) ? ~u : (u | 0x80000000u);
}
__device__ __forceinline__ float dec(unsigned k) {
  return (k & 0x80000000u) ? __uint_as_float(k ^ 0x80000000u) : __uint_as_float(~k);
}

// ---- fused setup: prep (lengths->topk/plen/keys-init), 3 weight
// transposes (f32 KxN -> bf16 NxK), bias2 = lin_b + b2. Block-role dispatch.
// Roles: [0,256) prep | [256,512) w1 | [512,1024) lin_w | [1024,1536) w2 |
//        [1536,1540) bias2.  Grid = 1540.
__global__ void k_setup(const int* __restrict__ text, int* __restrict__ topk,
                        int* __restrict__ plen, uint4* __restrict__ keys4,
                        const float* __restrict__ w1, bf16* __restrict__ w1t,
                        const float* __restrict__ lin_w, const float* __restrict__ w2,
                        bf16* __restrict__ b2t,
                        const float* __restrict__ lin_b, const float* __restrict__ b2,
                        float* __restrict__ bias2) {
  int blk = blockIdx.x, tid = threadIdx.x;
  if (blk < 256) {
    // prep: atten_sel[b,s] = -1 (s<len) / -0.0 (s>=len); top_k ties -> lowest
    // index first => topk order = [len..255] then [0..] up to k=76.
    int b = blk;
    keys4[b * 256 + tid] = make_uint4(0u, 0u, 0u, 0u);
    __shared__ int red[256];
    red[tid] = (text[b * SEQ + tid] != 0) ? 1 : 0;
    __syncthreads();
    for (int s = 128; s > 0; s >>= 1) {
      if (tid < s) red[tid] += red[tid + s];
      __syncthreads();
    }
    int len = red[0];
    int z = SEQ - len;
    if (tid < KSEL) topk[b * KSEL + tid] = (tid < z) ? (len + tid) : (tid - z);
    if (tid == 0) {
      int p = len - 2;
      plen[b] = p < 1 ? 1 : (p > KSEL ? KSEL : p);
    }
  } else if (blk < 1536) {
    const float* W;
    bf16* Wt;
    int N, ldo, bx, by;
    if (blk < 512)       { int t = blk - 256;  W = w1;    Wt = w1t;       N = 512;  ldo = 512;  bx = t & 15; by = t >> 4; }
    else if (blk < 1024) { int t = blk - 512;  W = lin_w; Wt = b2t;       N = 1024; ldo = 1024; bx = t & 31; by = t >> 5; }
    else                 { int t = blk - 1024; W = w2;    Wt = b2t + 512; N = 1024; ldo = 1024; bx = t & 31; by = t >> 5; }
    __shared__ float tile[32][33];
    int tx = tid & 31, ty = tid >> 5;
    int n = bx * 32 + tx, k0 = by * 32;
#pragma unroll
    for (int r = 0; r < 32; r += 8)
      tile[ty + r][tx] = W[(size_t)(k0 + ty + r) * N + n];
    __syncthreads();
#pragma unroll
    for (int r = 0; r < 32; r += 8)
      Wt[(size_t)(bx * 32 + ty + r) * ldo + k0 + tx] = (bf16)tile[tx][ty + r];
  } else {
    int i = (blk - 1536) * 256 + tid;
    bias2[i] = lin_b[i] + b2[i];
  }
}

// ---- gather + L2 normalize -> bf16 into A2 cols [0,512) ----
__global__ void k_gather(const float* __restrict__ feats, const int* __restrict__ topk,
                         bf16* __restrict__ A2) {
  int r = blockIdx.x;          // 0..19455
  int b = r / KSEL;
  int src = topk[r];
  const float4* row = (const float4*)(feats + ((size_t)b * SEQ + src) * DIN);
  int t = threadIdx.x;         // 128 threads
  float4 v = row[t];
  float ss = v.x * v.x + v.y * v.y + v.z * v.z + v.w * v.w;
#pragma unroll
  for (int o = 32; o > 0; o >>= 1) ss += __shfl_down(ss, o);
  __shared__ float wsum[2];
  if ((t & 63) == 0) wsum[t >> 6] = ss;
  __syncthreads();
  float total = wsum[0] + wsum[1];
  float inv = 1.0f / fmaxf(sqrtf(total), 1e-6f);
  bf16x4 o4;
  o4.x = (bf16)(v.x * inv);
  o4.y = (bf16)(v.y * inv);
  o4.z = (bf16)(v.z * inv);
  o4.w = (bf16)(v.w * inv);
  ((bf16x4*)A2)[(size_t)r * 256 + t] = o4;  // row stride 1024 bf16
}

// ---- 128x128 BK=64 bf16 GEMM -- m97 skeleton, compiler-scheduled ----
// Round-10 result: this structure (no inline asm, 4 blk/CU) gave the session
// best. Round-11 change: __launch_bounds__(256,5) -> 5 blocks/CU (LDS 5x32KB
// = 160KB exact; VGPR cap 102 >= observed ~90). GEMM2's 1216-block grid now
// fits the 1280-block device capacity in ONE round -- removes the 192-block
// tail (~30% of GEMM2 wall time at 4 blk/CU).
//   * BK=64, single 32KB buffer, plain __syncthreads
//   * r5-proven XOR swizzle: LDS 16B-slot s of row R holds k-chunk s^(R&7)
//     (pre-swizzled global source, linear gload_lds dest) -> 0 bank conflicts
//   * bijective XCD chunk swizzle on the 1D grid (grid % 8 == 0)
// EPI=1: bf16 C into Cb + column BN partials. EPI=2: masked per-batch max
// -> global atomicMax on enc() keys (no C write).
template<int EPI>
__global__ __launch_bounds__(256, 5)
void k_gemm(const bf16* __restrict__ A, int lda, const bf16* __restrict__ Bt, int ldb,
            const float* __restrict__ bias, bf16* __restrict__ Cb, int ldc, int Kext,
            int nbx, float* __restrict__ part, const int* __restrict__ plen,
            unsigned* __restrict__ keys) {
  __shared__ __align__(16) bf16 As[128 * 64];
  __shared__ __align__(16) bf16 Bs[128 * 64];
  const int q = gridDim.x >> 3;
  const int wg = (blockIdx.x & 7) * q + (blockIdx.x >> 3);
  const int bx = wg % nbx, by = wg / nbx;
  const int m0 = by * 128, n0 = bx * 128;
  const int tid = threadIdx.x, w = tid >> 6, lane = tid & 63;
  const int wr = (w >> 1) * 64, wc = (w & 1) * 64;
  const int srow = lane >> 3;                 // 0..7 within an 8-row stage call
  const int scol = ((lane & 7) ^ srow) * 8;   // pre-swizzled source column
  const bf16* Ag = A + (size_t)(m0 + w * 32 + srow) * lda + scol;
  const bf16* Bg = Bt + (size_t)(n0 + w * 32 + srow) * ldb + scol;
  f32x4 acc[4][4] = {};
  const int fr = lane & 15, fg = lane >> 4;

  for (int kt = 0; kt < Kext; kt += 64) {
    __syncthreads();                          // WAR: everyone done reading
#pragma unroll
    for (int c = 0; c < 4; ++c) {
      gload16(Ag + (size_t)(c * 8) * lda + kt, &As[(w * 32 + c * 8) * 64]);
      gload16(Bg + (size_t)(c * 8) * ldb + kt, &Bs[(w * 32 + c * 8) * 64]);
    }
    __syncthreads();                          // compiler emits vmcnt(0) drain
#pragma unroll
    for (int kk = 0; kk < 2; ++kk) {
      const int slot = ((kk << 2) | fg) ^ (fr & 7);
      bf16x8 af[4], bfr[4];
#pragma unroll
      for (int i = 0; i < 4; ++i)
        af[i] = *(const bf16x8*)&As[(wr + i * 16 + fr) * 64 + slot * 8];
#pragma unroll
      for (int j = 0; j < 4; ++j)
        bfr[j] = *(const bf16x8*)&Bs[(wc + j * 16 + fr) * 64 + slot * 8];
#pragma unroll
      for (int i = 0; i < 4; ++i)
#pragma unroll
        for (int j = 0; j < 4; ++j)
          acc[i][j] = __builtin_amdgcn_mfma_f32_16x16x32_bf16(af[i], bfr[j], acc[i][j], 0, 0, 0);
    }
  }

  float bv[4];
#pragma unroll
  for (int j = 0; j < 4; ++j) bv[j] = bias[n0 + wc + j * 16 + fr];

  if (EPI == 1) {
    float s[4] = {0, 0, 0, 0}, qq_[4] = {0, 0, 0, 0};
#pragma unroll
    for (int i = 0; i < 4; ++i)
#pragma unroll
      for (int v = 0; v < 4; ++v) {
        int r = m0 + wr + i * 16 + fg * 4 + v;
        bf16* crow = Cb + (size_t)r * ldc + n0 + wc + fr;
#pragma unroll
        for (int j = 0; j < 4; ++j) {
          float val = acc[i][j][v] + bv[j];
          crow[j * 16] = (bf16)val;      // bf16 h_pre into A2 H-half
          s[j] += val;                   // stats stay f32-exact
          qq_[j] += val * val;
        }
      }
    // deterministic reduce over fg (lanes +32, +16), then cross-wave via LDS
#pragma unroll
    for (int j = 0; j < 4; ++j) {
      s[j] += __shfl_down(s[j], 32); s[j] += __shfl_down(s[j], 16);
      qq_[j] += __shfl_down(qq_[j], 32); qq_[j] += __shfl_down(qq_[j], 16);
    }
    __syncthreads();
    float* red = (float*)&As[0];  // scratch: [w][j][fr] sums, +256 sq
    if (lane < 16) {
#pragma unroll
      for (int j = 0; j < 4; ++j) {
        red[(w * 4 + j) * 16 + lane] = s[j];
        red[256 + (w * 4 + j) * 16 + lane] = qq_[j];
      }
    }
    __syncthreads();
    if (tid < 128) {
      int c = tid;  // block-local column; waves {c>>6, (c>>6)+2} contributed
      int wsel = c >> 6, jj = (c >> 4) & 3, ff = c & 15;
      float ss = red[(wsel * 4 + jj) * 16 + ff] + red[((wsel + 2) * 4 + jj) * 16 + ff];
      float qs = red[256 + (wsel * 4 + jj) * 16 + ff] +
                 red[256 + ((wsel + 2) * 4 + jj) * 16 + ff];
      part[by * 512 + n0 + c] = ss;
      part[PARTQ + by * 512 + n0 + c] = qs;
    }
  } else {
    const float NEG = -__builtin_huge_valf();
    int cur_b = -1, pl = 0;
    bool any = false;
    float cm[4] = {NEG, NEG, NEG, NEG};
#pragma unroll
    for (int i = 0; i < 4; ++i)
#pragma unroll
      for (int v = 0; v < 4; ++v) {
        int gr = m0 + wr + i * 16 + fg * 4 + v;  // monotone over (i,v)
        int b = gr / KSEL;
        if (b != cur_b) {
          if (any) {
#pragma unroll
            for (int j = 0; j < 4; ++j)
              atomicMax(&keys[(size_t)cur_b * DEMB + n0 + wc + j * 16 + fr], enc(cm[j]));
          }
          cur_b = b;
          pl = plen[b];
          any = false;
#pragma unroll
          for (int j = 0; j < 4; ++j) cm[j] = NEG;
        }
        if (gr - b * KSEL < pl) {
          any = true;
#pragma unroll
          for (int j = 0; j < 4; ++j) cm[j] = fmaxf(cm[j], acc[i][j][v] + bv[j]);
        }
      }
    if (any) {
#pragma unroll
      for (int j = 0; j < 4; ++j)
        atomicMax(&keys[(size_t)cur_b * DEMB + n0 + wc + j * 16 + fr], enc(cm[j]));
    }
  }
}

// ---- BN stats stage A: 38 blocks x 4 tile-rows tree reduce ----
__global__ void k_bnredA(const float* __restrict__ part, float* __restrict__ part2) {
  int i = blockIdx.x, t = threadIdx.x;  // cols 2t, 2t+1
  float s0 = 0, s1 = 0, q0 = 0, q1 = 0;
  for (int j = 0; j < 4; ++j) {
    const float* p = part + (size_t)(i * 4 + j) * 512 + t * 2;
    float2 v = *(const float2*)p;
    float2 u = *(const float2*)(p + PARTQ);
    s0 += v.x; s1 += v.y; q0 += u.x; q1 += u.y;
  }
  part2[i * 512 + t * 2] = s0;
  part2[i * 512 + t * 2 + 1] = s1;
  part2[NRED * 512 + i * 512 + t * 2] = q0;
  part2[NRED * 512 + i * 512 + t * 2 + 1] = q1;
}

// ---- BN stats stage B: scale/shift per column ----
__global__ void k_bnstats(const float* __restrict__ part2, const float* __restrict__ g1,
                          const float* __restrict__ be1, float* __restrict__ bns) {
  int c = threadIdx.x;  // 512
  float s = 0, q = 0;
  for (int i = 0; i < NRED; ++i) {
    s += part2[i * 512 + c];
    q += part2[NRED * 512 + i * 512 + c];
  }
  const float invn = 1.0f / (float)MROWS;
  float mean = s * invn;
  float var = q * invn - mean * mean;  // biased, matches jnp.var
  float sc = rsqrtf(var + 1e-5f) * g1[c];
  bns[c] = sc;
  bns[512 + c] = be1[c] - mean * sc;
}

// ---- BN apply + ReLU, in place on A2 cols [512,1024) (bf16) ----
__global__ void k_bnapply(bf16x8* __restrict__ A2v, const float* __restrict__ bns) {
  size_t idx = (size_t)blockIdx.x * 256 + threadIdx.x;  // 1,245,184 chunks
  size_t row = idx >> 6;
  int c = (int)(idx & 63);                 // 8-col chunk within H half
  bf16x8* p = A2v + row * 128 + 64 + c;    // row stride 1024 bf16 = 128 chunks
  bf16x8 v = *p;
  int c8 = c * 8;
  const float4 s0 = *(const float4*)(bns + c8);
  const float4 s1 = *(const float4*)(bns + c8 + 4);
  const float4 h0 = *(const float4*)(bns + 512 + c8);
  const float4 h1 = *(const float4*)(bns + 512 + c8 + 4);
  bf16x8 o;
  o[0] = (bf16)fmaxf(fmaf((float)v[0], s0.x, h0.x), 0.0f);
  o[1] = (bf16)fmaxf(fmaf((float)v[1], s0.y, h0.y), 0.0f);
  o[2] = (bf16)fmaxf(fmaf((float)v[2], s0.z, h0.z), 0.0f);
  o[3] = (bf16)fmaxf(fmaf((float)v[3], s0.w, h0.w), 0.0f);
  o[4] = (bf16)fmaxf(fmaf((float)v[4], s1.x, h1.x), 0.0f);
  o[5] = (bf16)fmaxf(fmaf((float)v[5], s1.y, h1.y), 0.0f);
  o[6] = (bf16)fmaxf(fmaf((float)v[6], s1.z, h1.z), 0.0f);
  o[7] = (bf16)fmaxf(fmaf((float)v[7], s1.w, h1.w), 0.0f);
  *p = o;
}

// ---- decode pooled keys -> f32 output ----
__global__ void k_decode(const unsigned* __restrict__ keys, float* __restrict__ out) {
  int i = blockIdx.x * 256 + threadIdx.x;
  out[i] = dec(keys[i]);
}

extern "C" void kernel_launch(void* const* d_in, const int* in_sizes, int n_in,
                              void* d_out, int out_size, void* d_ws, size_t ws_size,
                              hipStream_t stream) {
  const float* features = (const float*)d_in[0];
  const int*   text     = (const int*)d_in[1];
  // d_in[2] = atten: provably unused (row eos is overwritten with -1 before use)
  const float* lin_w    = (const float*)d_in[3];
  const float* lin_b    = (const float*)d_in[4];
  const float* w1       = (const float*)d_in[5];
  const float* b1       = (const float*)d_in[6];
  const float* g1       = (const float*)d_in[7];
  const float* be1      = (const float*)d_in[8];
  const float* w2       = (const float*)d_in[9];
  const float* b2       = (const float*)d_in[10];
  float* out = (float*)d_out;
  char* ws = (char*)d_ws;

  // ws layout (bytes)
  int*      topk  = (int*)(ws + 0);           // 77,824
  int*      plen  = (int*)(ws + 77824);       // 1,024
  float*    bns   = (float*)(ws + 78848);     // 4,096 (scale[512], shift[512])
  float*    bias2 = (float*)(ws + 82944);     // 4,096
  float*    part  = (float*)(ws + 87040);     // 622,592 ([2][152][512] f32)
  float*    part2 = (float*)(ws + 709632);    // 155,648 ([2][38][512] f32)
  bf16*     w1t   = (bf16*)(ws + 865280);     // 524,288   (512 x 512)
  bf16*     b2t   = (bf16*)(ws + 1389568);    // 2,097,152 (1024 x 1024: [lin_w ; w2]^T)
  bf16*     A2    = (bf16*)(ws + 3486720);    // 39,845,888 (19456 x 1024: [X | H])
  unsigned* keys  = (unsigned*)(ws + 43332608); // 1,048,576 (256 x 1024 u32)

  k_setup<<<1540, 256, 0, stream>>>(text, topk, plen, (uint4*)keys,
                                    w1, w1t, lin_w, w2, b2t, lin_b, b2, bias2);
  k_gather<<<MROWS, 128, 0, stream>>>(features, topk, A2);
  // H_pre = X @ w1 + b1 -> bf16 into A2[:,512:1024], + fused BN partial stats
  k_gemm<1><<<MT128 * 4, 256, 0, stream>>>(A2, 1024, w1t, 512, b1, A2 + 512, 1024,
                                           512, 4, part, nullptr, nullptr);
  k_bnredA<<<NRED, 256, 0, stream>>>(part, part2);
  k_bnstats<<<1, 512, 0, stream>>>(part2, g1, be1, bns);
  k_bnapply<<<4864, 256, 0, stream>>>((bf16x8*)A2, bns);
  // [X|H] @ [lin_w ; w2] + (lin_b + b2), fused masked max-pool via atomicMax
  k_gemm<2><<<MT128 * 8, 256, 0, stream>>>(A2, 1024, b2t, 1024, bias2, nullptr, 0,
                                           1024, 8, nullptr, plen, keys);
  k_decode<<<BSZ * DEMB / 256, 256, 0, stream>>>(keys, out);
}

// Round 14
// 119.487 us; speedup vs baseline: 1.7384x; 1.7384x over previous
//
#include <hip/hip_runtime.h>
#include <hip/hip_bf16.h>

typedef __bf16 bf16;
typedef __bf16 bf16x4 __attribute__((ext_vector_type(4)));
typedef __bf16 bf16x8 __attribute__((ext_vector_type(8)));
typedef float  f32x4  __attribute__((ext_vector_type(4)));

#define BSZ   256
#define SEQ   256
#define DIN   512
#define DEMB  1024
#define KSEL  76
#define MROWS (BSZ * KSEL)   // 19456
#define MT128 (MROWS / 128)  // 152
#define MT256 (MROWS / 256)  // 76
#define PARTQ (MT128 * 512)
#define NRED  38             // stage-A reduce blocks (152/4)

__device__ __forceinline__ void gload16(const void* g, void* l) {
  __builtin_amdgcn_global_load_lds((const __attribute__((address_space(1))) void*)g,
                                   (__attribute__((address_space(3))) void*)l, 16, 0, 0);
}

// monotone float<->uint order-preserving encode for atomicMax.
// All enc() values are > 0, so zero-init acts as the -inf sentinel
// (every key provably receives >=1 update since plen[b] >= 1).
__device__ __forceinline__ unsigned enc(float v) {
  unsigned u = __float_as_uint(v);
  return (u & 0x80000000u) ? ~u : (u | 0x80000000u);
}
__device__ __forceinline__ float dec(unsigned k) {
  return (k & 0x80000000u) ? __uint_as_float(k ^ 0x80000000u) : __uint_as_float(~k);
}

// ---- fused setup: prep (lengths->topk/plen/keys-init), 3 weight
// transposes (f32 KxN -> bf16 NxK), bias2 = lin_b + b2. Block-role dispatch.
// Roles: [0,256) prep | [256,512) w1 | [512,1024) lin_w | [1024,1536) w2 |
//        [1536,1540) bias2.  Grid = 1540.
__global__ void k_setup(const int* __restrict__ text, int* __restrict__ topk,
                        int* __restrict__ plen, uint4* __restrict__ keys4,
                        const float* __restrict__ w1, bf16* __restrict__ w1t,
                        const float* __restrict__ lin_w, const float* __restrict__ w2,
                        bf16* __restrict__ b2t,
                        const float* __restrict__ lin_b, const float* __restrict__ b2,
                        float* __restrict__ bias2) {
  int blk = blockIdx.x, tid = threadIdx.x;
  if (blk < 256) {
    // prep: atten_sel[b,s] = -1 (s<len) / -0.0 (s>=len); top_k ties -> lowest
    // index first => topk order = [len..255] then [0..] up to k=76.
    int b = blk;
    keys4[b * 256 + tid] = make_uint4(0u, 0u, 0u, 0u);
    __shared__ int red[256];
    red[tid] = (text[b * SEQ + tid] != 0) ? 1 : 0;
    __syncthreads();
    for (int s = 128; s > 0; s >>= 1) {
      if (tid < s) red[tid] += red[tid + s];
      __syncthreads();
    }
    int len = red[0];
    int z = SEQ - len;
    if (tid < KSEL) topk[b * KSEL + tid] = (tid < z) ? (len + tid) : (tid - z);
    if (tid == 0) {
      int p = len - 2;
      plen[b] = p < 1 ? 1 : (p > KSEL ? KSEL : p);
    }
  } else if (blk < 1536) {
    const float* W;
    bf16* Wt;
    int N, ldo, bx, by;
    if (blk < 512)       { int t = blk - 256;  W = w1;    Wt = w1t;       N = 512;  ldo = 512;  bx = t & 15; by = t >> 4; }
    else if (blk < 1024) { int t = blk - 512;  W = lin_w; Wt = b2t;       N = 1024; ldo = 1024; bx = t & 31; by = t >> 5; }
    else                 { int t = blk - 1024; W = w2;    Wt = b2t + 512; N = 1024; ldo = 1024; bx = t & 31; by = t >> 5; }
    __shared__ float tile[32][33];
    int tx = tid & 31, ty = tid >> 5;
    int n = bx * 32 + tx, k0 = by * 32;
#pragma unroll
    for (int r = 0; r < 32; r += 8)
      tile[ty + r][tx] = W[(size_t)(k0 + ty + r) * N + n];
    __syncthreads();
#pragma unroll
    for (int r = 0; r < 32; r += 8)
      Wt[(size_t)(bx * 32 + ty + r) * ldo + k0 + tx] = (bf16)tile[tx][ty + r];
  } else {
    int i = (blk - 1536) * 256 + tid;
    bias2[i] = lin_b[i] + b2[i];
  }
}

// ---- gather + L2 normalize -> bf16 into A2 cols [0,512) ----
__global__ void k_gather(const float* __restrict__ feats, const int* __restrict__ topk,
                         bf16* __restrict__ A2) {
  int r = blockIdx.x;          // 0..19455
  int b = r / KSEL;
  int src = topk[r];
  const float4* row = (const float4*)(feats + ((size_t)b * SEQ + src) * DIN);
  int t = threadIdx.x;         // 128 threads
  float4 v = row[t];
  float ss = v.x * v.x + v.y * v.y + v.z * v.z + v.w * v.w;
#pragma unroll
  for (int o = 32; o > 0; o >>= 1) ss += __shfl_down(ss, o);
  __shared__ float wsum[2];
  if ((t & 63) == 0) wsum[t >> 6] = ss;
  __syncthreads();
  float total = wsum[0] + wsum[1];
  float inv = 1.0f / fmaxf(sqrtf(total), 1e-6f);
  bf16x4 o4;
  o4.x = (bf16)(v.x * inv);
  o4.y = (bf16)(v.y * inv);
  o4.z = (bf16)(v.z * inv);
  o4.w = (bf16)(v.w * inv);
  ((bf16x4*)A2)[(size_t)r * 256 + t] = o4;  // row stride 1024 bf16
}

// ---- GEMM1: 128x128 BK=64, compiler-scheduled (round-10 verified, 110us) ----
// NO inline asm. r5-proven XOR swizzle (16B-slot s of row R holds k-chunk
// s^(R&7); pre-swizzled global source, linear gload_lds dest) -> 0 conflicts.
// (256,4): r11 showed (256,5) forces VGPR->48 + scratch spill. Keep 4.
// Epilogue: bf16 C into Cb + column BN partials.
__global__ __launch_bounds__(256, 4)
void k_gemm1(const bf16* __restrict__ A, int lda, const bf16* __restrict__ Bt, int ldb,
             const float* __restrict__ bias, bf16* __restrict__ Cb, int ldc, int Kext,
             int nbx, float* __restrict__ part) {
  __shared__ __align__(16) bf16 As[128 * 64];
  __shared__ __align__(16) bf16 Bs[128 * 64];
  const int q = gridDim.x >> 3;
  const int wg = (blockIdx.x & 7) * q + (blockIdx.x >> 3);
  const int bx = wg % nbx, by = wg / nbx;
  const int m0 = by * 128, n0 = bx * 128;
  const int tid = threadIdx.x, w = tid >> 6, lane = tid & 63;
  const int wr = (w >> 1) * 64, wc = (w & 1) * 64;
  const int srow = lane >> 3;                 // 0..7 within an 8-row stage call
  const int scol = ((lane & 7) ^ srow) * 8;   // pre-swizzled source column
  const bf16* Ag = A + (size_t)(m0 + w * 32 + srow) * lda + scol;
  const bf16* Bg = Bt + (size_t)(n0 + w * 32 + srow) * ldb + scol;
  f32x4 acc[4][4] = {};
  const int fr = lane & 15, fg = lane >> 4;

  for (int kt = 0; kt < Kext; kt += 64) {
    __syncthreads();
#pragma unroll
    for (int c = 0; c < 4; ++c) {
      gload16(Ag + (size_t)(c * 8) * lda + kt, &As[(w * 32 + c * 8) * 64]);
      gload16(Bg + (size_t)(c * 8) * ldb + kt, &Bs[(w * 32 + c * 8) * 64]);
    }
    __syncthreads();
#pragma unroll
    for (int kk = 0; kk < 2; ++kk) {
      const int slot = ((kk << 2) | fg) ^ (fr & 7);
      bf16x8 af[4], bfr[4];
#pragma unroll
      for (int i = 0; i < 4; ++i)
        af[i] = *(const bf16x8*)&As[(wr + i * 16 + fr) * 64 + slot * 8];
#pragma unroll
      for (int j = 0; j < 4; ++j)
        bfr[j] = *(const bf16x8*)&Bs[(wc + j * 16 + fr) * 64 + slot * 8];
#pragma unroll
      for (int i = 0; i < 4; ++i)
#pragma unroll
        for (int j = 0; j < 4; ++j)
          acc[i][j] = __builtin_amdgcn_mfma_f32_16x16x32_bf16(af[i], bfr[j], acc[i][j], 0, 0, 0);
    }
  }

  float bv[4];
#pragma unroll
  for (int j = 0; j < 4; ++j) bv[j] = bias[n0 + wc + j * 16 + fr];

  float s[4] = {0, 0, 0, 0}, qq_[4] = {0, 0, 0, 0};
#pragma unroll
  for (int i = 0; i < 4; ++i)
#pragma unroll
    for (int v = 0; v < 4; ++v) {
      int r = m0 + wr + i * 16 + fg * 4 + v;
      bf16* crow = Cb + (size_t)r * ldc + n0 + wc + fr;
#pragma unroll
      for (int j = 0; j < 4; ++j) {
        float val = acc[i][j][v] + bv[j];
        crow[j * 16] = (bf16)val;      // bf16 h_pre into A2 H-half
        s[j] += val;                   // stats stay f32-exact
        qq_[j] += val * val;
      }
    }
  // deterministic reduce over fg (lanes +32, +16), then cross-wave via LDS
#pragma unroll
  for (int j = 0; j < 4; ++j) {
    s[j] += __shfl_down(s[j], 32); s[j] += __shfl_down(s[j], 16);
    qq_[j] += __shfl_down(qq_[j], 32); qq_[j] += __shfl_down(qq_[j], 16);
  }
  __syncthreads();
  float* red = (float*)&As[0];  // scratch: [w][j][fr] sums, +256 sq
  if (lane < 16) {
#pragma unroll
    for (int j = 0; j < 4; ++j) {
      red[(w * 4 + j) * 16 + lane] = s[j];
      red[256 + (w * 4 + j) * 16 + lane] = qq_[j];
    }
  }
  __syncthreads();
  if (tid < 128) {
    int c = tid;  // block-local column; waves {c>>6, (c>>6)+2} contributed
    int wsel = c >> 6, jj = (c >> 4) & 3, ff = c & 15;
    float ss = red[(wsel * 4 + jj) * 16 + ff] + red[((wsel + 2) * 4 + jj) * 16 + ff];
    float qs = red[256 + (wsel * 4 + jj) * 16 + ff] +
               red[256 + ((wsel + 2) * 4 + jj) * 16 + ff];
    part[by * 512 + n0 + c] = ss;
    part[PARTQ + by * 512 + n0 + c] = qs;
  }
}

// ---- GEMM2: 256x128 BK=64, 8 WAVES (512 threads!), fused max-pool ----
// r12/r13 NaN root cause: this kernel was launched with 256 threads (4
// waves) -- waves 4-7 never staged B rows 64-127 / A rows 128-255, and
// output rows 128-255 never updated keys -> keys==0 -> dec(0)=NaN.
// Launch is now 512 threads: 8 waves in a 4x2 grid of 64x64 wave tiles
// (wr=(w>>1)*64 rows, wc=(w&1)*64 cols). Staging: each wave 4 A-gloads
// (rows w*32..w*32+31) + 2 B-gloads (rows w*16..w*16+15) -> full 256/128
// coverage. Same XOR swizzle + plain __syncthreads loop as k_gemm1.
// (512,4) = 2 blocks/CU: 16 waves/CU (same as r10), VGPR cap 128 (no
// r11-style spill), LDS 2x48KB=96KB. Grid 608 (%8=0 for XCD swizzle);
// FETCH per FLOP halves vs 128^2 (r6 measured ~35MB at this tile).
__global__ __launch_bounds__(512, 4)
void k_gemm2(const bf16* __restrict__ A, int lda, const bf16* __restrict__ Bt, int ldb,
             const float* __restrict__ bias, int Kext, int nbx,
             const int* __restrict__ plen, unsigned* __restrict__ keys) {
  __shared__ __align__(16) bf16 As[256 * 64];
  __shared__ __align__(16) bf16 Bs[128 * 64];
  const int q = gridDim.x >> 3;
  const int wg = (blockIdx.x & 7) * q + (blockIdx.x >> 3);
  const int bx = wg % nbx, by = wg / nbx;
  const int m0 = by * 256, n0 = bx * 128;
  const int tid = threadIdx.x, w = tid >> 6, lane = tid & 63;  // w = 0..7
  const int wr = (w >> 1) * 64, wc = (w & 1) * 64;   // 4x2 waves of 64x64
  const int srow = lane >> 3;                 // 0..7 within an 8-row stage call
  const int scol = ((lane & 7) ^ srow) * 8;   // pre-swizzled source column
  const bf16* Ag = A + (size_t)(m0 + w * 32 + srow) * lda + scol;
  const bf16* Bg = Bt + (size_t)(n0 + w * 16 + srow) * ldb + scol;
  f32x4 acc[4][4] = {};
  const int fr = lane & 15, fg = lane >> 4;

  for (int kt = 0; kt < Kext; kt += 64) {
    __syncthreads();
#pragma unroll
    for (int c = 0; c < 4; ++c)     // A: 256 rows, 32/wave
      gload16(Ag + (size_t)(c * 8) * lda + kt, &As[(w * 32 + c * 8) * 64]);
#pragma unroll
    for (int c = 0; c < 2; ++c)     // B: 128 rows, 16/wave
      gload16(Bg + (size_t)(c * 8) * ldb + kt, &Bs[(w * 16 + c * 8) * 64]);
    __syncthreads();
#pragma unroll
    for (int kk = 0; kk < 2; ++kk) {
      const int slot = ((kk << 2) | fg) ^ (fr & 7);
      bf16x8 af[4], bfr[4];
#pragma unroll
      for (int i = 0; i < 4; ++i)
        af[i] = *(const bf16x8*)&As[(wr + i * 16 + fr) * 64 + slot * 8];
#pragma unroll
      for (int j = 0; j < 4; ++j)
        bfr[j] = *(const bf16x8*)&Bs[(wc + j * 16 + fr) * 64 + slot * 8];
#pragma unroll
      for (int i = 0; i < 4; ++i)
#pragma unroll
        for (int j = 0; j < 4; ++j)
          acc[i][j] = __builtin_amdgcn_mfma_f32_16x16x32_bf16(af[i], bfr[j], acc[i][j], 0, 0, 0);
    }
  }

  float bv[4];
#pragma unroll
  for (int j = 0; j < 4; ++j) bv[j] = bias[n0 + wc + j * 16 + fr];

  const float NEG = -__builtin_huge_valf();
  int cur_b = -1, pl = 0;
  bool any = false;
  float cm[4] = {NEG, NEG, NEG, NEG};
#pragma unroll
  for (int i = 0; i < 4; ++i)
#pragma unroll
    for (int v = 0; v < 4; ++v) {
      int gr = m0 + wr + i * 16 + fg * 4 + v;  // monotone over (i,v)
      int b = gr / KSEL;
      if (b != cur_b) {
        if (any) {
#pragma unroll
          for (int j = 0; j < 4; ++j)
            atomicMax(&keys[(size_t)cur_b * DEMB + n0 + wc + j * 16 + fr], enc(cm[j]));
        }
        cur_b = b;
        pl = plen[b];
        any = false;
#pragma unroll
        for (int j = 0; j < 4; ++j) cm[j] = NEG;
      }
      if (gr - b * KSEL < pl) {
        any = true;
#pragma unroll
        for (int j = 0; j < 4; ++j) cm[j] = fmaxf(cm[j], acc[i][j][v] + bv[j]);
      }
    }
  if (any) {
#pragma unroll
    for (int j = 0; j < 4; ++j)
      atomicMax(&keys[(size_t)cur_b * DEMB + n0 + wc + j * 16 + fr], enc(cm[j]));
  }
}

// ---- BN stats stage A: 38 blocks x 4 tile-rows tree reduce ----
__global__ void k_bnredA(const float* __restrict__ part, float* __restrict__ part2) {
  int i = blockIdx.x, t = threadIdx.x;  // cols 2t, 2t+1
  float s0 = 0, s1 = 0, q0 = 0, q1 = 0;
  for (int j = 0; j < 4; ++j) {
    const float* p = part + (size_t)(i * 4 + j) * 512 + t * 2;
    float2 v = *(const float2*)p;
    float2 u = *(const float2*)(p + PARTQ);
    s0 += v.x; s1 += v.y; q0 += u.x; q1 += u.y;
  }
  part2[i * 512 + t * 2] = s0;
  part2[i * 512 + t * 2 + 1] = s1;
  part2[NRED * 512 + i * 512 + t * 2] = q0;
  part2[NRED * 512 + i * 512 + t * 2 + 1] = q1;
}

// ---- BN stats stage B: scale/shift per column ----
__global__ void k_bnstats(const float* __restrict__ part2, const float* __restrict__ g1,
                          const float* __restrict__ be1, float* __restrict__ bns) {
  int c = threadIdx.x;  // 512
  float s = 0, q = 0;
  for (int i = 0; i < NRED; ++i) {
    s += part2[i * 512 + c];
    q += part2[NRED * 512 + i * 512 + c];
  }
  const float invn = 1.0f / (float)MROWS;
  float mean = s * invn;
  float var = q * invn - mean * mean;  // biased, matches jnp.var
  float sc = rsqrtf(var + 1e-5f) * g1[c];
  bns[c] = sc;
  bns[512 + c] = be1[c] - mean * sc;
}

// ---- BN apply + ReLU, in place on A2 cols [512,1024) (bf16) ----
__global__ void k_bnapply(bf16x8* __restrict__ A2v, const float* __restrict__ bns) {
  size_t idx = (size_t)blockIdx.x * 256 + threadIdx.x;  // 1,245,184 chunks
  size_t row = idx >> 6;
  int c = (int)(idx & 63);                 // 8-col chunk within H half
  bf16x8* p = A2v + row * 128 + 64 + c;    // row stride 1024 bf16 = 128 chunks
  bf16x8 v = *p;
  int c8 = c * 8;
  const float4 s0 = *(const float4*)(bns + c8);
  const float4 s1 = *(const float4*)(bns + c8 + 4);
  const float4 h0 = *(const float4*)(bns + 512 + c8);
  const float4 h1 = *(const float4*)(bns + 512 + c8 + 4);
  bf16x8 o;
  o[0] = (bf16)fmaxf(fmaf((float)v[0], s0.x, h0.x), 0.0f);
  o[1] = (bf16)fmaxf(fmaf((float)v[1], s0.y, h0.y), 0.0f);
  o[2] = (bf16)fmaxf(fmaf((float)v[2], s0.z, h0.z), 0.0f);
  o[3] = (bf16)fmaxf(fmaf((float)v[3], s0.w, h0.w), 0.0f);
  o[4] = (bf16)fmaxf(fmaf((float)v[4], s1.x, h1.x), 0.0f);
  o[5] = (bf16)fmaxf(fmaf((float)v[5], s1.y, h1.y), 0.0f);
  o[6] = (bf16)fmaxf(fmaf((float)v[6], s1.z, h1.z), 0.0f);
  o[7] = (bf16)fmaxf(fmaf((float)v[7], s1.w, h1.w), 0.0f);
  *p = o;
}

// ---- decode pooled keys -> f32 output ----
__global__ void k_decode(const unsigned* __restrict__ keys, float* __restrict__ out) {
  int i = blockIdx.x * 256 + threadIdx.x;
  out[i] = dec(keys[i]);
}

extern "C" void kernel_launch(void* const* d_in, const int* in_sizes, int n_in,
                              void* d_out, int out_size, void* d_ws, size_t ws_size,
                              hipStream_t stream) {
  const float* features = (const float*)d_in[0];
  const int*   text     = (const int*)d_in[1];
  // d_in[2] = atten: provably unused (row eos is overwritten with -1 before use)
  const float* lin_w    = (const float*)d_in[3];
  const float* lin_b    = (const float*)d_in[4];
  const float* w1       = (const float*)d_in[5];
  const float* b1       = (const float*)d_in[6];
  const float* g1       = (const float*)d_in[7];
  const float* be1      = (const float*)d_in[8];
  const float* w2       = (const float*)d_in[9];
  const float* b2       = (const float*)d_in[10];
  float* out = (float*)d_out;
  char* ws = (char*)d_ws;

  // ws layout (bytes)
  int*      topk  = (int*)(ws + 0);           // 77,824
  int*      plen  = (int*)(ws + 77824);       // 1,024
  float*    bns   = (float*)(ws + 78848);     // 4,096 (scale[512], shift[512])
  float*    bias2 = (float*)(ws + 82944);     // 4,096
  float*    part  = (float*)(ws + 87040);     // 622,592 ([2][152][512] f32)
  float*    part2 = (float*)(ws + 709632);    // 155,648 ([2][38][512] f32)
  bf16*     w1t   = (bf16*)(ws + 865280);     // 524,288   (512 x 512)
  bf16*     b2t   = (bf16*)(ws + 1389568);    // 2,097,152 (1024 x 1024: [lin_w ; w2]^T)
  bf16*     A2    = (bf16*)(ws + 3486720);    // 39,845,888 (19456 x 1024: [X | H])
  unsigned* keys  = (unsigned*)(ws + 43332608); // 1,048,576 (256 x 1024 u32)

  k_setup<<<1540, 256, 0, stream>>>(text, topk, plen, (uint4*)keys,
                                    w1, w1t, lin_w, w2, b2t, lin_b, b2, bias2);
  k_gather<<<MROWS, 128, 0, stream>>>(features, topk, A2);
  // H_pre = X @ w1 + b1 -> bf16 into A2[:,512:1024], + fused BN partial stats
  k_gemm1<<<MT128 * 4, 256, 0, stream>>>(A2, 1024, w1t, 512, b1, A2 + 512, 1024,
                                         512, 4, part);
  k_bnredA<<<NRED, 256, 0, stream>>>(part, part2);
  k_bnstats<<<1, 512, 0, stream>>>(part2, g1, be1, bns);
  k_bnapply<<<4864, 256, 0, stream>>>((bf16x8*)A2, bns);
  // [X|H] @ [lin_w ; w2] + (lin_b + b2), fused masked max-pool via atomicMax
  k_gemm2<<<MT256 * 8, 512, 0, stream>>>(A2, 1024, b2t, 1024, bias2, 1024, 8,
                                         plen, keys);
  k_decode<<<BSZ * DEMB / 256, 256, 0, stream>>>(keys, out);
}

// Round 15
// 110.141 us; speedup vs baseline: 1.8859x; 1.0849x over previous
//
#include <hip/hip_runtime.h>
#include <hip/hip_bf16.h>

typedef __bf16 bf16;
typedef __bf16 bf16x4 __attribute__((ext_vector_type(4)));
typedef __bf16 bf16x8 __attribute__((ext_vector_type(8)));
typedef float  f32x4  __attribute__((ext_vector_type(4)));

#define BSZ   256
#define SEQ   256
#define DIN   512
#define DEMB  1024
#define KSEL  76
#define MROWS (BSZ * KSEL)   // 19456
#define MT128 (MROWS / 128)  // 152
#define PARTQ (MT128 * 512)
#define NRED  38             // stage-A reduce blocks (152/4)

__device__ __forceinline__ void gload16(const void* g, void* l) {
  __builtin_amdgcn_global_load_lds((const __attribute__((address_space(1))) void*)g,
                                   (__attribute__((address_space(3))) void*)l, 16, 0, 0);
}

// monotone float<->uint order-preserving encode for atomicMax.
// All enc() values are > 0, so zero-init acts as the -inf sentinel
// (every key provably receives >=1 update since plen[b] >= 1).
__device__ __forceinline__ unsigned enc(float v) {
  unsigned u = __float_as_uint(v);
  return (u & 0x80000000u) ? ~u : (u | 0x80000000u);
}
__device__ __forceinline__ float dec(unsigned k) {
  return (k & 0x80000000u) ? __uint_as_float(k ^ 0x80000000u) : __uint_as_float(~k);
}

// ---- fused setup: prep (lengths->topk/plen/keys-init), 3 weight
// transposes (f32 KxN -> bf16 NxK), bias2 = lin_b + b2. Block-role dispatch.
// Roles: [0,256) prep | [256,512) w1 | [512,1024) lin_w | [1024,1536) w2 |
//        [1536,1540) bias2.  Grid = 1540.
__global__ void k_setup(const int* __restrict__ text, int* __restrict__ topk,
                        int* __restrict__ plen, uint4* __restrict__ keys4,
                        const float* __restrict__ w1, bf16* __restrict__ w1t,
                        const float* __restrict__ lin_w, const float* __restrict__ w2,
                        bf16* __restrict__ b2t,
                        const float* __restrict__ lin_b, const float* __restrict__ b2,
                        float* __restrict__ bias2) {
  int blk = blockIdx.x, tid = threadIdx.x;
  if (blk < 256) {
    // prep: atten_sel[b,s] = -1 (s<len) / -0.0 (s>=len); top_k ties -> lowest
    // index first => topk order = [len..255] then [0..] up to k=76.
    int b = blk;
    keys4[b * 256 + tid] = make_uint4(0u, 0u, 0u, 0u);
    __shared__ int red[256];
    red[tid] = (text[b * SEQ + tid] != 0) ? 1 : 0;
    __syncthreads();
    for (int s = 128; s > 0; s >>= 1) {
      if (tid < s) red[tid] += red[tid + s];
      __syncthreads();
    }
    int len = red[0];
    int z = SEQ - len;
    if (tid < KSEL) topk[b * KSEL + tid] = (tid < z) ? (len + tid) : (tid - z);
    if (tid == 0) {
      int p = len - 2;
      plen[b] = p < 1 ? 1 : (p > KSEL ? KSEL : p);
    }
  } else if (blk < 1536) {
    const float* W;
    bf16* Wt;
    int N, ldo, bx, by;
    if (blk < 512)       { int t = blk - 256;  W = w1;    Wt = w1t;       N = 512;  ldo = 512;  bx = t & 15; by = t >> 4; }
    else if (blk < 1024) { int t = blk - 512;  W = lin_w; Wt = b2t;       N = 1024; ldo = 1024; bx = t & 31; by = t >> 5; }
    else                 { int t = blk - 1024; W = w2;    Wt = b2t + 512; N = 1024; ldo = 1024; bx = t & 31; by = t >> 5; }
    __shared__ float tile[32][33];
    int tx = tid & 31, ty = tid >> 5;
    int n = bx * 32 + tx, k0 = by * 32;
#pragma unroll
    for (int r = 0; r < 32; r += 8)
      tile[ty + r][tx] = W[(size_t)(k0 + ty + r) * N + n];
    __syncthreads();
#pragma unroll
    for (int r = 0; r < 32; r += 8)
      Wt[(size_t)(bx * 32 + ty + r) * ldo + k0 + tx] = (bf16)tile[tx][ty + r];
  } else {
    int i = (blk - 1536) * 256 + tid;
    bias2[i] = lin_b[i] + b2[i];
  }
}

// ---- gather + L2 normalize -> bf16 into A2 cols [0,512) ----
__global__ void k_gather(const float* __restrict__ feats, const int* __restrict__ topk,
                         bf16* __restrict__ A2) {
  int r = blockIdx.x;          // 0..19455
  int b = r / KSEL;
  int src = topk[r];
  const float4* row = (const float4*)(feats + ((size_t)b * SEQ + src) * DIN);
  int t = threadIdx.x;         // 128 threads
  float4 v = row[t];
  float ss = v.x * v.x + v.y * v.y + v.z * v.z + v.w * v.w;
#pragma unroll
  for (int o = 32; o > 0; o >>= 1) ss += __shfl_down(ss, o);
  __shared__ float wsum[2];
  if ((t & 63) == 0) wsum[t >> 6] = ss;
  __syncthreads();
  float total = wsum[0] + wsum[1];
  float inv = 1.0f / fmaxf(sqrtf(total), 1e-6f);
  bf16x4 o4;
  o4.x = (bf16)(v.x * inv);
  o4.y = (bf16)(v.y * inv);
  o4.z = (bf16)(v.z * inv);
  o4.w = (bf16)(v.w * inv);
  ((bf16x4*)A2)[(size_t)r * 256 + t] = o4;  // row stride 1024 bf16
}

// ---- 128x128 BK=64 bf16 GEMM -- m97 skeleton, compiler-scheduled ----
// SESSION OPTIMUM (round 10, 110.2us total). Every perturbation measured
// and lost: hand-asm pipelines r5-r9 (81-100us GEMM2, compiler wins),
// (256,5) r11 (VGPR spill, 207us), 256x128/(512,4) r14 (2 blk/CU kills
// cross-block TLP, 119.5us). Keep: NO inline asm, BK=64, single 32KB
// buffer, plain __syncthreads, 4 blocks/CU, r5-proven XOR swizzle
// (16B-slot s of row R holds k-chunk s^(R&7); pre-swizzled global source,
// linear gload_lds dest -> 0 bank conflicts), bijective XCD chunk swizzle.
// EPI=1: bf16 C into Cb + column BN partials. EPI=2: masked per-batch max
// -> global atomicMax on enc() keys (no C write).
template<int EPI>
__global__ __launch_bounds__(256, 4)
void k_gemm(const bf16* __restrict__ A, int lda, const bf16* __restrict__ Bt, int ldb,
            const float* __restrict__ bias, bf16* __restrict__ Cb, int ldc, int Kext,
            int nbx, float* __restrict__ part, const int* __restrict__ plen,
            unsigned* __restrict__ keys) {
  __shared__ __align__(16) bf16 As[128 * 64];
  __shared__ __align__(16) bf16 Bs[128 * 64];
  const int q = gridDim.x >> 3;
  const int wg = (blockIdx.x & 7) * q + (blockIdx.x >> 3);
  const int bx = wg % nbx, by = wg / nbx;
  const int m0 = by * 128, n0 = bx * 128;
  const int tid = threadIdx.x, w = tid >> 6, lane = tid & 63;
  const int wr = (w >> 1) * 64, wc = (w & 1) * 64;
  const int srow = lane >> 3;                 // 0..7 within an 8-row stage call
  const int scol = ((lane & 7) ^ srow) * 8;   // pre-swizzled source column
  const bf16* Ag = A + (size_t)(m0 + w * 32 + srow) * lda + scol;
  const bf16* Bg = Bt + (size_t)(n0 + w * 32 + srow) * ldb + scol;
  f32x4 acc[4][4] = {};
  const int fr = lane & 15, fg = lane >> 4;

  for (int kt = 0; kt < Kext; kt += 64) {
    __syncthreads();                          // WAR: everyone done reading
#pragma unroll
    for (int c = 0; c < 4; ++c) {
      gload16(Ag + (size_t)(c * 8) * lda + kt, &As[(w * 32 + c * 8) * 64]);
      gload16(Bg + (size_t)(c * 8) * ldb + kt, &Bs[(w * 32 + c * 8) * 64]);
    }
    __syncthreads();                          // compiler emits vmcnt(0) drain
#pragma unroll
    for (int kk = 0; kk < 2; ++kk) {
      const int slot = ((kk << 2) | fg) ^ (fr & 7);
      bf16x8 af[4], bfr[4];
#pragma unroll
      for (int i = 0; i < 4; ++i)
        af[i] = *(const bf16x8*)&As[(wr + i * 16 + fr) * 64 + slot * 8];
#pragma unroll
      for (int j = 0; j < 4; ++j)
        bfr[j] = *(const bf16x8*)&Bs[(wc + j * 16 + fr) * 64 + slot * 8];
#pragma unroll
      for (int i = 0; i < 4; ++i)
#pragma unroll
        for (int j = 0; j < 4; ++j)
          acc[i][j] = __builtin_amdgcn_mfma_f32_16x16x32_bf16(af[i], bfr[j], acc[i][j], 0, 0, 0);
    }
  }

  float bv[4];
#pragma unroll
  for (int j = 0; j < 4; ++j) bv[j] = bias[n0 + wc + j * 16 + fr];

  if (EPI == 1) {
    float s[4] = {0, 0, 0, 0}, qq_[4] = {0, 0, 0, 0};
#pragma unroll
    for (int i = 0; i < 4; ++i)
#pragma unroll
      for (int v = 0; v < 4; ++v) {
        int r = m0 + wr + i * 16 + fg * 4 + v;
        bf16* crow = Cb + (size_t)r * ldc + n0 + wc + fr;
#pragma unroll
        for (int j = 0; j < 4; ++j) {
          float val = acc[i][j][v] + bv[j];
          crow[j * 16] = (bf16)val;      // bf16 h_pre into A2 H-half
          s[j] += val;                   // stats stay f32-exact
          qq_[j] += val * val;
        }
      }
    // deterministic reduce over fg (lanes +32, +16), then cross-wave via LDS
#pragma unroll
    for (int j = 0; j < 4; ++j) {
      s[j] += __shfl_down(s[j], 32); s[j] += __shfl_down(s[j], 16);
      qq_[j] += __shfl_down(qq_[j], 32); qq_[j] += __shfl_down(qq_[j], 16);
    }
    __syncthreads();
    float* red = (float*)&As[0];  // scratch: [w][j][fr] sums, +256 sq
    if (lane < 16) {
#pragma unroll
      for (int j = 0; j < 4; ++j) {
        red[(w * 4 + j) * 16 + lane] = s[j];
        red[256 + (w * 4 + j) * 16 + lane] = qq_[j];
      }
    }
    __syncthreads();
    if (tid < 128) {
      int c = tid;  // block-local column; waves {c>>6, (c>>6)+2} contributed
      int wsel = c >> 6, jj = (c >> 4) & 3, ff = c & 15;
      float ss = red[(wsel * 4 + jj) * 16 + ff] + red[((wsel + 2) * 4 + jj) * 16 + ff];
      float qs = red[256 + (wsel * 4 + jj) * 16 + ff] +
                 red[256 + ((wsel + 2) * 4 + jj) * 16 + ff];
      part[by * 512 + n0 + c] = ss;
      part[PARTQ + by * 512 + n0 + c] = qs;
    }
  } else {
    const float NEG = -__builtin_huge_valf();
    int cur_b = -1, pl = 0;
    bool any = false;
    float cm[4] = {NEG, NEG, NEG, NEG};
#pragma unroll
    for (int i = 0; i < 4; ++i)
#pragma unroll
      for (int v = 0; v < 4; ++v) {
        int gr = m0 + wr + i * 16 + fg * 4 + v;  // monotone over (i,v)
        int b = gr / KSEL;
        if (b != cur_b) {
          if (any) {
#pragma unroll
            for (int j = 0; j < 4; ++j)
              atomicMax(&keys[(size_t)cur_b * DEMB + n0 + wc + j * 16 + fr], enc(cm[j]));
          }
          cur_b = b;
          pl = plen[b];
          any = false;
#pragma unroll
          for (int j = 0; j < 4; ++j) cm[j] = NEG;
        }
        if (gr - b * KSEL < pl) {
          any = true;
#pragma unroll
          for (int j = 0; j < 4; ++j) cm[j] = fmaxf(cm[j], acc[i][j][v] + bv[j]);
        }
      }
    if (any) {
#pragma unroll
      for (int j = 0; j < 4; ++j)
        atomicMax(&keys[(size_t)cur_b * DEMB + n0 + wc + j * 16 + fr], enc(cm[j]));
    }
  }
}

// ---- BN stats stage A: 38 blocks x 4 tile-rows tree reduce ----
__global__ void k_bnredA(const float* __restrict__ part, float* __restrict__ part2) {
  int i = blockIdx.x, t = threadIdx.x;  // cols 2t, 2t+1
  float s0 = 0, s1 = 0, q0 = 0, q1 = 0;
  for (int j = 0; j < 4; ++j) {
    const float* p = part + (size_t)(i * 4 + j) * 512 + t * 2;
    float2 v = *(const float2*)p;
    float2 u = *(const float2*)(p + PARTQ);
    s0 += v.x; s1 += v.y; q0 += u.x; q1 += u.y;
  }
  part2[i * 512 + t * 2] = s0;
  part2[i * 512 + t * 2 + 1] = s1;
  part2[NRED * 512 + i * 512 + t * 2] = q0;
  part2[NRED * 512 + i * 512 + t * 2 + 1] = q1;
}

// ---- BN stats stage B: scale/shift per column ----
__global__ void k_bnstats(const float* __restrict__ part2, const float* __restrict__ g1,
                          const float* __restrict__ be1, float* __restrict__ bns) {
  int c = threadIdx.x;  // 512
  float s = 0, q = 0;
  for (int i = 0; i < NRED; ++i) {
    s += part2[i * 512 + c];
    q += part2[NRED * 512 + i * 512 + c];
  }
  const float invn = 1.0f / (float)MROWS;
  float mean = s * invn;
  float var = q * invn - mean * mean;  // biased, matches jnp.var
  float sc = rsqrtf(var + 1e-5f) * g1[c];
  bns[c] = sc;
  bns[512 + c] = be1[c] - mean * sc;
}

// ---- BN apply + ReLU, in place on A2 cols [512,1024) (bf16) ----
__global__ void k_bnapply(bf16x8* __restrict__ A2v, const float* __restrict__ bns) {
  size_t idx = (size_t)blockIdx.x * 256 + threadIdx.x;  // 1,245,184 chunks
  size_t row = idx >> 6;
  int c = (int)(idx & 63);                 // 8-col chunk within H half
  bf16x8* p = A2v + row * 128 + 64 + c;    // row stride 1024 bf16 = 128 chunks
  bf16x8 v = *p;
  int c8 = c * 8;
  const float4 s0 = *(const float4*)(bns + c8);
  const float4 s1 = *(const float4*)(bns + c8 + 4);
  const float4 h0 = *(const float4*)(bns + 512 + c8);
  const float4 h1 = *(const float4*)(bns + 512 + c8 + 4);
  bf16x8 o;
  o[0] = (bf16)fmaxf(fmaf((float)v[0], s0.x, h0.x), 0.0f);
  o[1] = (bf16)fmaxf(fmaf((float)v[1], s0.y, h0.y), 0.0f);
  o[2] = (bf16)fmaxf(fmaf((float)v[2], s0.z, h0.z), 0.0f);
  o[3] = (bf16)fmaxf(fmaf((float)v[3], s0.w, h0.w), 0.0f);
  o[4] = (bf16)fmaxf(fmaf((float)v[4], s1.x, h1.x), 0.0f);
  o[5] = (bf16)fmaxf(fmaf((float)v[5], s1.y, h1.y), 0.0f);
  o[6] = (bf16)fmaxf(fmaf((float)v[6], s1.z, h1.z), 0.0f);
  o[7] = (bf16)fmaxf(fmaf((float)v[7], s1.w, h1.w), 0.0f);
  *p = o;
}

// ---- decode pooled keys -> f32 output ----
__global__ void k_decode(const unsigned* __restrict__ keys, float* __restrict__ out) {
  int i = blockIdx.x * 256 + threadIdx.x;
  out[i] = dec(keys[i]);
}

extern "C" void kernel_launch(void* const* d_in, const int* in_sizes, int n_in,
                              void* d_out, int out_size, void* d_ws, size_t ws_size,
                              hipStream_t stream) {
  const float* features = (const float*)d_in[0];
  const int*   text     = (const int*)d_in[1];
  // d_in[2] = atten: provably unused (row eos is overwritten with -1 before use)
  const float* lin_w    = (const float*)d_in[3];
  const float* lin_b    = (const float*)d_in[4];
  const float* w1       = (const float*)d_in[5];
  const float* b1       = (const float*)d_in[6];
  const float* g1       = (const float*)d_in[7];
  const float* be1      = (const float*)d_in[8];
  const float* w2       = (const float*)d_in[9];
  const float* b2       = (const float*)d_in[10];
  float* out = (float*)d_out;
  char* ws = (char*)d_ws;

  // ws layout (bytes)
  int*      topk  = (int*)(ws + 0);           // 77,824
  int*      plen  = (int*)(ws + 77824);       // 1,024
  float*    bns   = (float*)(ws + 78848);     // 4,096 (scale[512], shift[512])
  float*    bias2 = (float*)(ws + 82944);     // 4,096
  float*    part  = (float*)(ws + 87040);     // 622,592 ([2][152][512] f32)
  float*    part2 = (float*)(ws + 709632);    // 155,648 ([2][38][512] f32)
  bf16*     w1t   = (bf16*)(ws + 865280);     // 524,288   (512 x 512)
  bf16*     b2t   = (bf16*)(ws + 1389568);    // 2,097,152 (1024 x 1024: [lin_w ; w2]^T)
  bf16*     A2    = (bf16*)(ws + 3486720);    // 39,845,888 (19456 x 1024: [X | H])
  unsigned* keys  = (unsigned*)(ws + 43332608); // 1,048,576 (256 x 1024 u32)

  k_setup<<<1540, 256, 0, stream>>>(text, topk, plen, (uint4*)keys,
                                    w1, w1t, lin_w, w2, b2t, lin_b, b2, bias2);
  k_gather<<<MROWS, 128, 0, stream>>>(features, topk, A2);
  // H_pre = X @ w1 + b1 -> bf16 into A2[:,512:1024], + fused BN partial stats
  k_gemm<1><<<MT128 * 4, 256, 0, stream>>>(A2, 1024, w1t, 512, b1, A2 + 512, 1024,
                                           512, 4, part, nullptr, nullptr);
  k_bnredA<<<NRED, 256, 0, stream>>>(part, part2);
  k_bnstats<<<1, 512, 0, stream>>>(part2, g1, be1, bns);
  k_bnapply<<<4864, 256, 0, stream>>>((bf16x8*)A2, bns);
  // [X|H] @ [lin_w ; w2] + (lin_b + b2), fused masked max-pool via atomicMax
  k_gemm<2><<<MT128 * 8, 256, 0, stream>>>(A2, 1024, b2t, 1024, bias2, nullptr, 0,
                                           1024, 8, nullptr, plen, keys);
  k_decode<<<BSZ * DEMB / 256, 256, 0, stream>>>(keys, out);
}